// Round 8
// baseline (1914.023 us; speedup 1.0000x reference)
//
#include <hip/hip_runtime.h>
#include <hip/hip_bf16.h>

// MnistModelDP: 2-layer LSTM (H=512) over T=64 frames of 128, B=2048, then proj to 10.
// v7: PERSISTENT kernel — all 65 rounds in one launch, manual grid barrier (monotonic
// counter, relaxed agent atomics). Removes per-round launch + L2-flush overhead that
// capped v4-v6 at ~24 us/round. Cross-block h traffic via agent-scope (sc1) loads/stores
// (per-XCD L2 not coherent); weights/c/x XCD-private or immutable -> plain cached, weights
// stay L2-hot across all rounds. Tile BM=128 x BN=256, 8 waves, BK=64 dbuf staging via
// global_load_lds w=16 + granule-XOR swizzle (proven v4/v6). fp16 MFMA, fp32 accum.

typedef _Float16 f16x8 __attribute__((ext_vector_type(8)));
typedef float f32x4 __attribute__((ext_vector_type(4)));

#define Bsz 2048
#define Lsz 8192
#define Tsz 64
#define NBLK 256

__global__ void cvt_f32_f16(const float* __restrict__ src, _Float16* __restrict__ dst, int n4) {
    int stride = gridDim.x * blockDim.x;
    for (int i = blockIdx.x * blockDim.x + threadIdx.x; i < n4; i += stride) {
        float4 v = ((const float4*)src)[i];
        union { _Float16 h[4]; ushort4 u; } o;
        o.h[0] = (_Float16)v.x; o.h[1] = (_Float16)v.y;
        o.h[2] = (_Float16)v.z; o.h[3] = (_Float16)v.w;
        ((ushort4*)dst)[i] = o.u;
    }
}

// pack [2048, K1] W_ih (f32) and [2048, 512] W_hh (f32) -> [2048, K1+512] f16
__global__ void pack_w(const float* __restrict__ Wih, const float* __restrict__ Whh,
                       _Float16* __restrict__ dst, int K1) {
    int KT = K1 + 512;
    int n4 = 2048 * KT / 4;
    int stride = gridDim.x * blockDim.x;
    for (int i = blockIdx.x * blockDim.x + threadIdx.x; i < n4; i += stride) {
        int row = i / (KT / 4);
        int col = (i % (KT / 4)) * 4;
        const float* s = (col < K1) ? (Wih + (size_t)row * K1 + col)
                                    : (Whh + (size_t)row * 512 + (col - K1));
        float4 v = *(const float4*)s;
        union { _Float16 h[4]; ushort4 u; } o;
        o.h[0] = (_Float16)v.x; o.h[1] = (_Float16)v.y;
        o.h[2] = (_Float16)v.z; o.h[3] = (_Float16)v.w;
        ((ushort4*)dst)[i] = o.u;
    }
}

__device__ __forceinline__ float fsig(float x)  { return 1.0f / (1.0f + __expf(-x)); }
__device__ __forceinline__ float ftanh(float x) { return 1.0f - 2.0f / (__expf(2.0f * x) + 1.0f); }

// aux=0: normal cached; aux=16 (SC1): agent-scope -> bypasses (non-coherent) L2, reads L3.
template<int AUX>
__device__ __forceinline__ void gll16(const _Float16* src, char* dst) {
    __builtin_amdgcn_global_load_lds(
        (const __attribute__((address_space(1))) void*)src,
        (__attribute__((address_space(3))) void*)dst, 16, 0, AUX);
}

// Stage one BK=64 K-slice: B (256 gate-cols x 64) at buf+0 (32KB), A (128 rows x 64) at
// buf+32768 (16KB). LDS rows 128 B; slot s of row r holds source granule (s ^ (r&7)) via
// pre-swizzled SOURCE + linear global_load_lds dest (both-sides rule, proven v4/v6).
template<int K1, int AUX1>
__device__ __forceinline__ void stage_v7(
    const _Float16* __restrict__ A1, int lda1,   // k < K1 (x for layer0 [cached], h0 for layer1 [sc1])
    const _Float16* __restrict__ A2,              // k >= K1: h_prev (sc1)
    const _Float16* __restrict__ Wcat,            // weights (cached, L2-hot)
    int hcb, int rowtile, int k0, char* buf, int tid)
{
    constexpr int KT = K1 + 512;
    const int wv = tid >> 6;
    // B tile: rows j = gate*64 + lc -> W row gate*512 + hcb*64 + lc
#pragma unroll
    for (int qq = 0; qq < 4; ++qq) {
        const int j  = qq * 64 + (tid >> 3);
        const int cg = (((tid & 7) ^ (j & 7)) << 3);
        const int wrow = ((j >> 6) << 9) + hcb * 64 + (j & 63);
        gll16<0>(Wcat + (size_t)wrow * KT + k0 + cg, buf + qq * 8192 + wv * 1024);
    }
    // A tile: 128 rows. k0 multiple of 64 and K1 % 64 == 0 -> branch is uniform.
#pragma unroll
    for (int qq = 0; qq < 2; ++qq) {
        const int row  = qq * 64 + (tid >> 3);
        const int cg   = (((tid & 7) ^ (row & 7)) << 3);
        const int brow = rowtile * 128 + row;
        char* d = buf + 32768 + qq * 8192 + wv * 1024;
        if (k0 < K1) gll16<AUX1>(A1 + (size_t)brow * lda1 + k0 + cg, d);
        else         gll16<16>(A2 + (size_t)brow * 512 + (k0 - K1) + cg, d);
    }
}

// One LSTM step tile: 128 batch rows x 256 gate-cols (64 hcols x 4 gates), K = K1+512.
// 8 waves as 2(row) x 4(col) grid of 64x64 wave tiles. BK=64, double-buffered staging.
// MFMA 16x16x32 f16 layouts (passed v2/v4/v6):
//   A frag: lane l elem j -> A[l&15][(l>>4)*8+j]; B frag: lane l -> W[col l&15][(l>>4)*8+j]
//   C/D: lane l reg r -> C[(l>>4)*4+r][l&15]
template<int K1, int AUX1>
__device__ __forceinline__ void step_v7(
    const _Float16* __restrict__ A1, int lda1,
    const _Float16* __restrict__ A2,
    const _Float16* __restrict__ Wcat,
    const float* __restrict__ bias,
    float* __restrict__ c,
    _Float16* __restrict__ h_out,
    int rowtile, int hcb, char* lds)
{
    constexpr int KT  = K1 + 512;
    constexpr int NIT = KT / 64;
    const int tid = threadIdx.x;
    const int ln  = tid & 63;
    const int wv  = tid >> 6;
    const int llo = ln & 15, lhi = ln >> 4;
    const int wr  = wv >> 2, wc = wv & 3;   // wave row tile (x64), wave col tile (x64)

    f32x4 acc[4][4] = {};                   // [row-frag mi][col-frag cf]

    stage_v7<K1, AUX1>(A1, lda1, A2, Wcat, hcb, rowtile, 0, lds, tid);
    __syncthreads();

#pragma unroll 2
    for (int it = 0; it < NIT; ++it) {
        char* cur = lds + (it & 1) * 49152;
        if (it + 1 < NIT)   // prefetch next K-slice into other buffer
            stage_v7<K1, AUX1>(A1, lda1, A2, Wcat, hcb, rowtile, (it + 1) * 64,
                               lds + ((it + 1) & 1) * 49152, tid);
#pragma unroll
        for (int ks = 0; ks < 2; ++ks) {
            const int gsw = (((ks * 4 + lhi) ^ (llo & 7)) << 4);   // swizzled granule byte
            f16x8 a[4], b[4];
#pragma unroll
            for (int mi = 0; mi < 4; ++mi)
                a[mi] = *(const f16x8*)(cur + 32768 + (wr * 64 + mi * 16 + llo) * 128 + gsw);
#pragma unroll
            for (int cf = 0; cf < 4; ++cf)
                b[cf] = *(const f16x8*)(cur + (wc * 64 + cf * 16 + llo) * 128 + gsw);
#pragma unroll
            for (int mi = 0; mi < 4; ++mi)
#pragma unroll
                for (int cf = 0; cf < 4; ++cf)
                    acc[mi][cf] = __builtin_amdgcn_mfma_f32_16x16x32_f16(
                        a[mi], b[cf], acc[mi][cf], 0, 0, 0);
        }
        __syncthreads();
    }

    // gates exchange: acc -> LDS f32 [128 rows][256 cols] (128 KB overlay, after barrier)
    float* gl = (float*)lds;
#pragma unroll
    for (int mi = 0; mi < 4; ++mi)
#pragma unroll
        for (int cf = 0; cf < 4; ++cf) {
            const int col = wc * 64 + cf * 16 + llo;
#pragma unroll
            for (int rr = 0; rr < 4; ++rr) {
                const int row = wr * 64 + mi * 16 + lhi * 4 + rr;
                gl[row * 256 + col] = acc[mi][cf][rr];
            }
        }
    __syncthreads();

    // fused cell update: 2 adjacent hcols x 8 rows per thread (coalesced dword h stores).
    const int lc2  = (tid & 31) << 1;
    const int ro   = tid >> 5;              // 0..15
    const int hcol = hcb * 64 + lc2;
    const float bi0 = bias[hcol],        bi1 = bias[hcol + 1];
    const float bf0 = bias[512 + hcol],  bf1 = bias[512 + hcol + 1];
    const float bg0 = bias[1024 + hcol], bg1 = bias[1024 + hcol + 1];
    const float bo0 = bias[1536 + hcol], bo1 = bias[1536 + hcol + 1];
#pragma unroll
    for (int i = 0; i < 8; ++i) {
        const int row = i * 16 + ro;
        const float* g0 = gl + row * 256 + lc2;
        float iv0 = g0[0]   + bi0, iv1 = g0[1]   + bi1;
        float fv0 = g0[64]  + bf0, fv1 = g0[65]  + bf1;
        float gv0 = g0[128] + bg0, gv1 = g0[129] + bg1;
        float ov0 = g0[192] + bo0, ov1 = g0[193] + bo1;
        const size_t base = (size_t)(rowtile * 128 + row) * 512 + hcol;
        float2 cc = *(const float2*)&c[base];
        float cn0 = fsig(fv0) * cc.x + fsig(iv0) * ftanh(gv0);
        float cn1 = fsig(fv1) * cc.y + fsig(iv1) * ftanh(gv1);
        float hn0 = fsig(ov0) * ftanh(cn0);
        float hn1 = fsig(ov1) * ftanh(cn1);
        float2 cw; cw.x = cn0; cw.y = cn1;
        *(float2*)&c[base] = cw;
        union { _Float16 h2[2]; unsigned u; } hp;
        hp.h2[0] = (_Float16)hn0; hp.h2[1] = (_Float16)hn1;
        // agent-scope store -> visible at L3 for other XCDs' sc1 staging loads
        __hip_atomic_store((unsigned*)(h_out + base), hp.u,
                           __ATOMIC_RELAXED, __HIP_MEMORY_SCOPE_AGENT);
    }
}

// Persistent: 256 blocks (1/CU via 128KB LDS -> all co-resident). Decode: x=bid&7 (XCD),
// q=bid>>3: layer=q&1, rowtile=q>>1, hcb=x -> each XCD owns one hcol strip per layer
// (weights + c slices L2-resident for the entire 64-step sequence).
__global__ __launch_bounds__(512, 1) void lstm_persist(
    const _Float16* __restrict__ xb16,
    const _Float16* __restrict__ Wc0, const float* __restrict__ b0, float* __restrict__ c0,
    _Float16* __restrict__ h00, _Float16* __restrict__ h01,
    const _Float16* __restrict__ Wc1, const float* __restrict__ b1, float* __restrict__ c1,
    _Float16* __restrict__ h10, _Float16* __restrict__ h11,
    unsigned* __restrict__ cnt)
{
    __shared__ __align__(16) char lds[131072];
    const int bid     = blockIdx.x;
    const int x       = bid & 7;
    const int q       = bid >> 3;
    const int layer   = q & 1;
    const int rowtile = q >> 1;   // 0..15
    const int hcb     = x;        // 0..7

    for (int r = 0; r <= Tsz; ++r) {
        if (layer == 0) {
            if (r < Tsz) {
                const int t0 = r;
                const _Float16* hr = (t0 & 1) ? h01 : h00;
                _Float16*       hw = (t0 & 1) ? h00 : h01;
                step_v7<128, 0>(xb16 + (size_t)t0 * 128, Lsz, hr, Wc0, b0, c0, hw,
                                rowtile, hcb, lds);
            }
        } else {
            if (r >= 1) {
                const int t1 = r - 1;
                const _Float16* h0in = ((t1 + 1) & 1) ? h01 : h00;  // h0 output of step t1
                const _Float16* hr   = (t1 & 1) ? h11 : h10;
                _Float16*       hw   = (t1 & 1) ? h10 : h11;
                step_v7<512, 16>(h0in, 512, hr, Wc1, b1, c1, hw, rowtile, hcb, lds);
            }
        }
        if (r < Tsz) {
            // grid barrier: __syncthreads drains each wave's vmcnt (h stores at L3), then
            // monotonic-counter arrive/spin with relaxed agent atomics.
            __syncthreads();
            if (threadIdx.x == 0) {
                __hip_atomic_fetch_add(cnt, 1u, __ATOMIC_RELAXED, __HIP_MEMORY_SCOPE_AGENT);
                const unsigned target = (unsigned)NBLK * (r + 1);
                while (__hip_atomic_load(cnt, __ATOMIC_RELAXED, __HIP_MEMORY_SCOPE_AGENT) < target)
                    __builtin_amdgcn_s_sleep(1);
            }
            __syncthreads();
            __builtin_amdgcn_sched_barrier(0);
        }
    }
}

__global__ void proj_kernel(const _Float16* __restrict__ h1,
                            const float* __restrict__ Wout,  // [10, 512]
                            const float* __restrict__ bout,  // [10]
                            float* __restrict__ out)         // [2048, 10]
{
    int tid = blockIdx.x * blockDim.x + threadIdx.x;
    if (tid >= Bsz * 10) return;
    int b = tid / 10, o = tid % 10;
    float s = bout[o];
    const _Float16* hrow = h1 + (size_t)b * 512;
    const float* wrow = Wout + (size_t)o * 512;
    for (int k = 0; k < 512; ++k) s += (float)hrow[k] * wrow[k];
    out[tid] = s;
}

extern "C" void kernel_launch(void* const* d_in, const int* in_sizes, int n_in,
                              void* d_out, int out_size, void* d_ws, size_t ws_size,
                              hipStream_t stream) {
    const float* xb    = (const float*)d_in[0];
    const float* W_ih0 = (const float*)d_in[1];
    const float* W_hh0 = (const float*)d_in[2];
    const float* b0    = (const float*)d_in[3];
    const float* W_ih1 = (const float*)d_in[4];
    const float* W_hh1 = (const float*)d_in[5];
    const float* b1    = (const float*)d_in[6];
    const float* W_out = (const float*)d_in[7];
    const float* b_out = (const float*)d_in[8];
    float* out = (float*)d_out;

    char* ws = (char*)d_ws;
    size_t off = 0;
    auto alloc = [&](size_t bytes) -> void* {
        void* p = ws + off;
        off += (bytes + 255) & ~(size_t)255;
        return p;
    };
    _Float16* xb16 = (_Float16*)alloc((size_t)Bsz * Lsz * 2);
    _Float16* Wc0  = (_Float16*)alloc((size_t)2048 * 640 * 2);
    _Float16* Wc1  = (_Float16*)alloc((size_t)2048 * 1024 * 2);
    _Float16* h00  = (_Float16*)alloc((size_t)Bsz * 512 * 2);
    _Float16* h01  = (_Float16*)alloc((size_t)Bsz * 512 * 2);
    _Float16* h10  = (_Float16*)alloc((size_t)Bsz * 512 * 2);
    _Float16* h11  = (_Float16*)alloc((size_t)Bsz * 512 * 2);
    float* c0 = (float*)alloc((size_t)Bsz * 512 * 4);
    float* c1 = (float*)alloc((size_t)Bsz * 512 * 4);
    unsigned* cnt = (unsigned*)alloc(256);

    cvt_f32_f16<<<2048, 256, 0, stream>>>(xb, xb16, Bsz * Lsz / 4);
    pack_w<<<1280, 256, 0, stream>>>(W_ih0, W_hh0, Wc0, 128);
    pack_w<<<2048, 256, 0, stream>>>(W_ih1, W_hh1, Wc1, 512);

    hipMemsetAsync(h00, 0, (size_t)Bsz * 512 * 2, stream);
    hipMemsetAsync(h10, 0, (size_t)Bsz * 512 * 2, stream);
    hipMemsetAsync(c0, 0, (size_t)Bsz * 512 * 4, stream);
    hipMemsetAsync(c1, 0, (size_t)Bsz * 512 * 4, stream);
    hipMemsetAsync(cnt, 0, 256, stream);   // barrier counter: reset every launch (determinism)

    lstm_persist<<<dim3(NBLK), 512, 0, stream>>>(
        xb16, Wc0, b0, c0, h00, h01, Wc1, b1, c1, h10, h11, cnt);

    // final h1 (step 63) written to h1[(63+1)&1] == h10
    proj_kernel<<<(Bsz * 10 + 255) / 256, 256, 0, stream>>>(h10, W_out, b_out, out);
}